// Round 1
// baseline (161.584 us; speedup 1.0000x reference)
//
#include <hip/hip_runtime.h>
#include <cstddef>
#include <cstdint>

#define BB 8
#define SS 256
#define EE 256
#define NN1 16
#define NN2 16
#define DD 100
#define QQ 768

// ---------------------------------------------------------------------------
// prep: blocks 0..15 -> per (b, layer) compute qk = 0.1 * Wk^T tanh(Wq q0 + bq)
//       blocks 16..23 -> per b inclusive scan of (input_ent != 0) -> rank (-1 = masked)
// ---------------------------------------------------------------------------
__global__ __launch_bounds__(256) void prep_kernel(
    const float* __restrict__ q, const int* __restrict__ ent,
    const float* __restrict__ Wq2, const float* __restrict__ bq2, const float* __restrict__ Wk2,
    const float* __restrict__ Wq1, const float* __restrict__ bq1, const float* __restrict__ Wk1,
    float* __restrict__ qk2o, float* __restrict__ qk1o, int* __restrict__ rk)
{
    const int blk = blockIdx.x, t = threadIdx.x;
    if (blk < 16) {
        const int b = blk >> 1, layer = blk & 1;   // layer 0 -> (Wq2,..), layer 1 -> (Wq1,..)
        const float* Wq = layer ? Wq1 : Wq2;
        const float* bq = layer ? bq1 : bq2;
        const float* Wk = layer ? Wk1 : Wk2;
        float* qko      = layer ? qk1o : qk2o;
        __shared__ float s_q[QQ];
        __shared__ float s_qi[DD];
        for (int i = t; i < QQ; i += 256) s_q[i] = q[(size_t)b * SS * QQ + i]; // q[b,0,:]
        __syncthreads();
        const int r = t & 7;
        for (int d = t >> 3; d < DD; d += 32) {
            float acc = 0.f;
            for (int i = r; i < QQ; i += 8) acc += Wq[(size_t)d * QQ + i] * s_q[i];
            acc += __shfl_xor(acc, 1, 8);
            acc += __shfl_xor(acc, 2, 8);
            acc += __shfl_xor(acc, 4, 8);
            if (r == 0) s_qi[d] = tanhf(acc + bq[d]);
        }
        __syncthreads();
        if (t < DD) {
            float acc = 0.f;
            for (int d = 0; d < DD; ++d) acc += s_qi[d] * Wk[d * DD + t]; // (Wk^T q_i)[t]
            qko[b * DD + t] = 0.1f * acc;   // fold 1/sqrt(100)
        }
    } else {
        const int b = blk - 16;
        __shared__ int s_m[SS];
        const int m = (ent[b * SS + t] != 0) ? 1 : 0;
        s_m[t] = m;
        __syncthreads();
        for (int off = 1; off < SS; off <<= 1) {
            const int add = (t >= off) ? s_m[t - off] : 0;
            __syncthreads();
            s_m[t] += add;
            __syncthreads();
        }
        int rank = s_m[t] - 1;
        rank = rank < 0 ? 0 : (rank > EE - 1 ? EE - 1 : rank);
        rk[b * SS + t] = m ? rank : -1;
    }
}

// ---------------------------------------------------------------------------
// main: one block per (b,e). Layer2 over 16 n1 tiles, then layer1, emit comb[b,e,0:200].
// ---------------------------------------------------------------------------
__global__ __launch_bounds__(256) void main_kernel(
    const float* __restrict__ k1, const float* __restrict__ v1,
    const float* __restrict__ k2, const float* __restrict__ v2,
    const float* __restrict__ qk1g, const float* __restrict__ qk2g,
    float* __restrict__ comb)
{
    const int be = blockIdx.x;
    const int b  = be >> 8;
    const int t  = threadIdx.x;

    __shared__ float s_k[NN2 * DD];      // 1600 floats
    __shared__ float s_v[NN2 * DD];
    __shared__ float s_c2[NN1 * DD];     // layer-2 outputs (combined2)
    __shared__ float s_qk[DD];
    __shared__ float s_logit[16];
    __shared__ float s_p[16];
    float4* sk4 = reinterpret_cast<float4*>(s_k);
    float4* sv4 = reinterpret_cast<float4*>(s_v);

    if (t < DD) s_qk[t] = qk2g[b * DD + t];

    const int gi = t >> 4;   // row index within tile (n2 for layer2, n1 for layer1)
    const int rr = t & 15;

    for (int n1 = 0; n1 < NN1; ++n1) {
        __syncthreads();   // protect s_k/s_v/s_p reuse (and initial s_qk write)
        const float4* gk = reinterpret_cast<const float4*>(k2 + (size_t)(be * NN1 + n1) * (NN2 * DD));
        const float4* gv = reinterpret_cast<const float4*>(v2 + (size_t)(be * NN1 + n1) * (NN2 * DD));
        for (int i = t; i < 400; i += 256) { sk4[i] = gk[i]; sv4[i] = gv[i]; }
        __syncthreads();

        // logits: 16 lanes per n2 row
        float acc = 0.f;
        for (int d = rr; d < DD; d += 16) acc += s_k[gi * DD + d] * s_qk[d];
        acc += __shfl_xor(acc, 1, 16);
        acc += __shfl_xor(acc, 2, 16);
        acc += __shfl_xor(acc, 4, 16);
        acc += __shfl_xor(acc, 8, 16);
        if (rr == 0) {
            float lg = acc;
            if (lg == 0.0f) lg = -10000.0f;
            lg = lg >= 0.f ? lg : 0.01f * lg;     // leaky_relu, slope .01
            s_logit[gi] = lg;
        }
        __syncthreads();
        if (t < 16) {
            const float lg = s_logit[t];
            float mx = lg;
            mx = fmaxf(mx, __shfl_xor(mx, 1, 16));
            mx = fmaxf(mx, __shfl_xor(mx, 2, 16));
            mx = fmaxf(mx, __shfl_xor(mx, 4, 16));
            mx = fmaxf(mx, __shfl_xor(mx, 8, 16));
            const float e = __expf(lg - mx);
            float sm = e;
            sm += __shfl_xor(sm, 1, 16);
            sm += __shfl_xor(sm, 2, 16);
            sm += __shfl_xor(sm, 4, 16);
            sm += __shfl_xor(sm, 8, 16);
            float p = e / sm;
            if (p == 0.0625f) p = 0.f;            // where(attn == 1/n, 0)
            s_p[t] = p;
        }
        __syncthreads();
        if (t < DD) {
            float a2 = 0.f;
            #pragma unroll
            for (int n2 = 0; n2 < NN2; ++n2) a2 += s_p[n2] * s_v[n2 * DD + t];
            s_c2[n1 * DD + t] = a2;
        }
    }

    // ---- layer 1 ----
    __syncthreads();
    if (t < DD) s_qk[t] = qk1g[b * DD + t];
    {
        const float4* gk = reinterpret_cast<const float4*>(k1 + (size_t)be * (NN1 * DD));
        const float4* gv = reinterpret_cast<const float4*>(v1 + (size_t)be * (NN1 * DD));
        for (int i = t; i < 400; i += 256) { sk4[i] = gk[i]; sv4[i] = gv[i]; }
    }
    __syncthreads();

    float acc = 0.f;
    for (int d = rr; d < DD; d += 16) acc += s_k[gi * DD + d] * s_qk[d];
    acc += __shfl_xor(acc, 1, 16);
    acc += __shfl_xor(acc, 2, 16);
    acc += __shfl_xor(acc, 4, 16);
    acc += __shfl_xor(acc, 8, 16);
    if (rr == 0) {
        float lg = acc;
        if (lg == 0.0f) lg = -10000.0f;
        lg = lg >= 0.f ? lg : 0.01f * lg;
        s_logit[gi] = lg;
    }
    __syncthreads();
    if (t < 16) {
        const float lg = s_logit[t];
        float mx = lg;
        mx = fmaxf(mx, __shfl_xor(mx, 1, 16));
        mx = fmaxf(mx, __shfl_xor(mx, 2, 16));
        mx = fmaxf(mx, __shfl_xor(mx, 4, 16));
        mx = fmaxf(mx, __shfl_xor(mx, 8, 16));
        const float e = __expf(lg - mx);
        float sm = e;
        sm += __shfl_xor(sm, 1, 16);
        sm += __shfl_xor(sm, 2, 16);
        sm += __shfl_xor(sm, 4, 16);
        sm += __shfl_xor(sm, 8, 16);
        float p = e / sm;
        if (p == 0.0625f) p = 0.f;
        s_p[t] = p;
    }
    __syncthreads();
    if (t < 2 * DD) {
        float a1 = 0.f;
        if (t < DD) {
            #pragma unroll
            for (int n1 = 0; n1 < NN1; ++n1) a1 += s_p[n1] * s_v[n1 * DD + t];
        } else {
            const int d = t - DD;
            #pragma unroll
            for (int n1 = 0; n1 < NN1; ++n1) a1 += s_p[n1] * s_c2[n1 * DD + d];
        }
        comb[(size_t)be * (2 * DD) + t] = a1;
    }
}

// ---------------------------------------------------------------------------
// gather: one block per (b,s)
// ---------------------------------------------------------------------------
__global__ __launch_bounds__(64) void gather_kernel(
    const float* __restrict__ comb, const int* __restrict__ rk, float* __restrict__ out)
{
    const int bs = blockIdx.x;
    const int b  = bs >> 8;
    const int t  = threadIdx.x;
    const int r  = rk[bs];
    float* o = out + (size_t)bs * (2 * DD);
    if (r < 0) {
        for (int d = t; d < 2 * DD; d += 64) o[d] = 0.f;
    } else {
        const float* src = comb + (size_t)(b * EE + r) * (2 * DD);
        for (int d = t; d < 2 * DD; d += 64) o[d] = src[d];
    }
}

extern "C" void kernel_launch(void* const* d_in, const int* in_sizes, int n_in,
                              void* d_out, int out_size, void* d_ws, size_t ws_size,
                              hipStream_t stream)
{
    const int*   ent = (const int*)d_in[0];
    const float* q   = (const float*)d_in[1];
    const float* k1  = (const float*)d_in[2];
    const float* v1  = (const float*)d_in[3];
    const float* k2  = (const float*)d_in[4];
    const float* v2  = (const float*)d_in[5];
    const float* Wq2 = (const float*)d_in[6];
    const float* bq2 = (const float*)d_in[7];
    const float* Wk2 = (const float*)d_in[8];
    const float* Wq1 = (const float*)d_in[9];
    const float* bq1 = (const float*)d_in[10];
    const float* Wk1 = (const float*)d_in[11];
    float* out = (float*)d_out;

    float* ws   = (float*)d_ws;
    float* qk2  = ws;                    // 800 floats
    float* qk1  = ws + 1024;             // 800 floats
    float* comb = ws + 4096;             // 8*256*200 = 409600 floats
    int*   rk   = (int*)(ws + 4096 + 409600);  // 2048 ints

    prep_kernel<<<24, 256, 0, stream>>>(q, ent, Wq2, bq2, Wk2, Wq1, bq1, Wk1, qk2, qk1, rk);
    main_kernel<<<BB * EE, 256, 0, stream>>>(k1, v1, k2, v2, qk1, qk2, comb);
    gather_kernel<<<BB * SS, 64, 0, stream>>>(comb, rk, out);
}